// Round 6
// baseline (79.375 us; speedup 1.0000x reference)
//
#include <hip/hip_runtime.h>
#include <hip/hip_bf16.h>

#define N_ 16
#define L_ 256
#define C_ 512
#define HW_ 1024
#define HEADS_ 16
#define DH_ 32

typedef unsigned short u16;
typedef unsigned int u32;
typedef __attribute__((ext_vector_type(8))) short short8_t;
typedef __attribute__((ext_vector_type(4))) float f32x4;
typedef __attribute__((ext_vector_type(2))) unsigned int u32x2;

__device__ __forceinline__ u16 f2bs(float f) {
    union { float f; u32 i; } x; x.f = f;
    u32 r = x.i + 0x7fffu + ((x.i >> 16) & 1u);
    return (u16)(r >> 16);
}
__device__ __forceinline__ u32 cvt_pk_bf16(float lo, float hi) {
    u32 r;
    asm("v_cvt_pk_bf16_f32 %0, %1, %2" : "=v"(r) : "v"(lo), "v"(hi));
    return r;
}
// convert 8 consecutive fp32 -> 8 bf16 (one short8 store)
__device__ __forceinline__ void cvt8(const float* __restrict__ src, void* dst) {
    float4 lo = *(const float4*)src;
    float4 hi = *(const float4*)(src + 4);
    union { u32 w[4]; short8_t v; } pk;
    pk.w[0] = cvt_pk_bf16(lo.x, lo.y);
    pk.w[1] = cvt_pk_bf16(lo.z, lo.w);
    pk.w[2] = cvt_pk_bf16(hi.x, hi.y);
    pk.w[3] = cvt_pk_bf16(hi.z, hi.w);
    *(short8_t*)dst = pk.v;
}

// ---------------------------------------------------------------------------
// proj_kernel: fused Q / K / V projections, fp32 inputs converted in-register.
//  blocks [0,512): KV path  — grid (64 m-tiles x 8 n-tiles) of token GEMM.
//  blocks [512,2560): QF path — grid (256 m-tiles x 8 n-tiles) of feature GEMM
//    (feature [c][pos] transposed on the fly via subtiled LDS + tr_b16 reads).
// Both: BM=BN=BK=64, 4 waves (2x2), granule-XOR-swizzled A/W tiles.
// ---------------------------------------------------------------------------
__global__ __launch_bounds__(256) void proj_kernel(
    const float* __restrict__ feature, const float* __restrict__ token,
    const float* __restrict__ wq, const float* __restrict__ bq,
    const float* __restrict__ wk, const float* __restrict__ bk,
    const float* __restrict__ wv, const float* __restrict__ bv,
    u16* __restrict__ Qout, u16* __restrict__ Kout, u16* __restrict__ Vt)
{
    __shared__ __align__(16) unsigned char smem[24576];

    const int t = threadIdx.x;
    const int lane = t & 63, wid = t >> 6;
    const int i16 = lane & 15, g = lane >> 4;
    const int wm = wid >> 1, wn = wid & 1;

    if (blockIdx.x < 512) {
        // ================= KV path =================
        u16* As  = (u16*)smem;
        u16* Bks = (u16*)(smem + 8192);
        u16* Bvs = (u16*)(smem + 16384);
        u16 (*LTo)[72] = (u16(*)[72])smem;

        const int m0 = (blockIdx.x & 63) * 64, n0 = (blockIdx.x >> 6) * 64;
        const int row_a = t >> 3, c8 = t & 7;

        f32x4 ak[2][2] = {{{0.f,0.f,0.f,0.f},{0.f,0.f,0.f,0.f}},
                          {{0.f,0.f,0.f,0.f},{0.f,0.f,0.f,0.f}}};
        f32x4 av[2][2] = {{{0.f,0.f,0.f,0.f},{0.f,0.f,0.f,0.f}},
                          {{0.f,0.f,0.f,0.f},{0.f,0.f,0.f,0.f}}};
        const float bk0 = bk[n0 + wn * 32 + i16];
        const float bk1 = bk[n0 + wn * 32 + 16 + i16];
        const float bv0 = bv[n0 + wn * 32 + i16];
        const float bv1 = bv[n0 + wn * 32 + 16 + i16];

        for (int c0 = 0; c0 < C_; c0 += 64) {
            __syncthreads();
            #pragma unroll
            for (int r = 0; r < 2; ++r) {
                const int m = row_a + r * 32;
                const int sw = m * 64 + ((c8 ^ (m & 7)) << 3);
                cvt8(&token[(size_t)(m0 + m) * C_ + c0 + c8 * 8], &As[sw]);
                cvt8(&wk[(size_t)(n0 + m) * C_ + c0 + c8 * 8], &Bks[sw]);
                cvt8(&wv[(size_t)(n0 + m) * C_ + c0 + c8 * 8], &Bvs[sw]);
            }
            __syncthreads();
            #pragma unroll
            for (int ks = 0; ks < 2; ++ks) {
                short8_t a[2], bbk[2], bbv[2];
                #pragma unroll
                for (int mt = 0; mt < 2; ++mt) {
                    const int m = wm * 32 + mt * 16 + i16;
                    a[mt] = *(const short8_t*)&As[m * 64 + ((((ks << 2) | g) ^ (m & 7)) << 3)];
                }
                #pragma unroll
                for (int nt = 0; nt < 2; ++nt) {
                    const int d = wn * 32 + nt * 16 + i16;
                    const int sw = d * 64 + ((((ks << 2) | g) ^ (d & 7)) << 3);
                    bbk[nt] = *(const short8_t*)&Bks[sw];
                    bbv[nt] = *(const short8_t*)&Bvs[sw];
                }
                #pragma unroll
                for (int mt = 0; mt < 2; ++mt)
                    #pragma unroll
                    for (int nt = 0; nt < 2; ++nt) {
                        ak[mt][nt] = __builtin_amdgcn_mfma_f32_16x16x32_bf16(
                            a[mt], bbk[nt], ak[mt][nt], 0, 0, 0);
                        av[mt][nt] = __builtin_amdgcn_mfma_f32_16x16x32_bf16(
                            a[mt], bbv[nt], av[mt][nt], 0, 0, 0);
                    }
            }
        }
        const int nb = m0 >> 8, l0 = m0 & 255;
        const size_t vtbase = (size_t)nb * C_ * L_;
        #pragma unroll
        for (int mt = 0; mt < 2; ++mt)
            #pragma unroll
            for (int nt = 0; nt < 2; ++nt) {
                const int d = n0 + wn * 32 + nt * 16 + i16;
                const float bb = nt ? bv1 : bv0;
                ushort4 w;
                w.x = f2bs(av[mt][nt][0] + bb);
                w.y = f2bs(av[mt][nt][1] + bb);
                w.z = f2bs(av[mt][nt][2] + bb);
                w.w = f2bs(av[mt][nt][3] + bb);
                const int l = l0 + wm * 32 + mt * 16 + g * 4;
                *(ushort4*)&Vt[vtbase + (size_t)d * L_ + l] = w;
            }
        __syncthreads();
        #pragma unroll
        for (int mt = 0; mt < 2; ++mt)
            #pragma unroll
            for (int nt = 0; nt < 2; ++nt) {
                const float bb = nt ? bk1 : bk0;
                #pragma unroll
                for (int r = 0; r < 4; ++r)
                    LTo[wm * 32 + mt * 16 + g * 4 + r][wn * 32 + nt * 16 + i16] =
                        f2bs(ak[mt][nt][r] + bb);
            }
        __syncthreads();
        #pragma unroll
        for (int rep = 0; rep < 2; ++rep) {
            const int m = (t >> 3) + rep * 32;
            const int cs = (t & 7) * 8;
            *(short8_t*)&Kout[(size_t)(m0 + m) * C_ + n0 + cs] = *(short8_t*)&LTo[m][cs];
        }
    } else {
        // ================= QF path =================
        u16* As = (u16*)smem;            // Wq tile [64][64] granule-swizzled
        u16* Bs = (u16*)(smem + 8192);   // feature subtiled [16 cb][4 pb][4][16]

        const int bid = blockIdx.x - 512;
        const int m0 = (bid & 255) * 64, n0 = (bid >> 8) * 64;
        const int n = m0 >> 10, pos0 = m0 & (HW_ - 1);
        const int row_a = t >> 3, c8 = t & 7;

        f32x4 acc[2][2] = {{{0.f,0.f,0.f,0.f},{0.f,0.f,0.f,0.f}},
                           {{0.f,0.f,0.f,0.f},{0.f,0.f,0.f,0.f}}};

        for (int c0 = 0; c0 < C_; c0 += 64) {
            __syncthreads();
            // stage Wq rows (fp32 -> bf16, granule-XOR swizzle)
            #pragma unroll
            for (int r = 0; r < 2; ++r) {
                const int m = row_a + r * 32;
                cvt8(&wq[(size_t)(n0 + m) * C_ + c0 + c8 * 8],
                     &As[m * 64 + ((c8 ^ (m & 7)) << 3)]);
            }
            // stage feature tile [64 c][64 pos]: 16 thr/row -> 256B segments
            #pragma unroll
            for (int ps = 0; ps < 4; ++ps) {
                const int row = ps * 16 + (t >> 4);
                const int px = (t & 15) * 4;
                float4 v = *(const float4*)&feature[
                    ((size_t)n * C_ + c0 + row) * HW_ + pos0 + px];
                ushort4 w;
                w.x = f2bs(v.x); w.y = f2bs(v.y);
                w.z = f2bs(v.z); w.w = f2bs(v.w);
                *(ushort4*)&Bs[(row >> 2) * 256 + (px >> 4) * 64 +
                               (row & 3) * 16 + (px & 15)] = w;
            }
            __syncthreads();
            // batched frag reads: 4x ds_read_b128 (A) + 8x tr_b16 (B), one wait
            short8_t a2[2][2], b2[2][2];
            #pragma unroll
            for (int ks = 0; ks < 2; ++ks)
                #pragma unroll
                for (int mt = 0; mt < 2; ++mt) {
                    const int m = wm * 32 + mt * 16 + i16;
                    a2[ks][mt] = *(const short8_t*)&As[m * 64 + ((((ks << 2) | g) ^ (m & 7)) << 3)];
                }
            #pragma unroll
            for (int ks = 0; ks < 2; ++ks)
                #pragma unroll
                for (int nt = 0; nt < 2; ++nt) {
                    const int pb = wn * 2 + nt;
                    const u32 vaddr = 8192 +
                        (u32)(ks * 32 + g * 8 + pb) * 128 + (u32)i16 * 2;
                    u32x2 lo, hi;
                    asm volatile("ds_read_b64_tr_b16 %0, %1"
                                 : "=v"(lo) : "v"(vaddr));
                    asm volatile("ds_read_b64_tr_b16 %0, %1 offset:512"
                                 : "=v"(hi) : "v"(vaddr));
                    union { u32 w[4]; short8_t v; } pk;
                    pk.w[0] = lo[0]; pk.w[1] = lo[1];
                    pk.w[2] = hi[0]; pk.w[3] = hi[1];
                    b2[ks][nt] = pk.v;
                }
            asm volatile("s_waitcnt lgkmcnt(0)" ::: "memory");
            __builtin_amdgcn_sched_barrier(0);
            #pragma unroll
            for (int ks = 0; ks < 2; ++ks)
                #pragma unroll
                for (int mt = 0; mt < 2; ++mt)
                    #pragma unroll
                    for (int nt = 0; nt < 2; ++nt)
                        acc[mt][nt] = __builtin_amdgcn_mfma_f32_16x16x32_bf16(
                            a2[ks][mt], b2[ks][nt], acc[mt][nt], 0, 0, 0);
        }
        // epilogue: lane holds 4 consecutive d (rows) for col pos
        #pragma unroll
        for (int mt = 0; mt < 2; ++mt) {
            const int dbase = wm * 32 + mt * 16 + g * 4;
            float4 b4 = *(const float4*)&bq[n0 + dbase];
            const float bb[4] = {b4.x, b4.y, b4.z, b4.w};
            #pragma unroll
            for (int nt = 0; nt < 2; ++nt) {
                const int pos = wn * 32 + nt * 16 + i16;
                ushort4 w;
                w.x = f2bs(acc[mt][nt][0] + bb[0]);
                w.y = f2bs(acc[mt][nt][1] + bb[1]);
                w.z = f2bs(acc[mt][nt][2] + bb[2]);
                w.w = f2bs(acc[mt][nt][3] + bb[3]);
                *(ushort4*)&Qout[(size_t)(m0 + pos) * C_ + n0 + dbase] = w;
            }
        }
    }
}

// ---------------------------------------------------------------------------
// attn v2.1 (unchanged from R5): swapped-QK MFMA, granule-swizzled K/V,
// in-register softmax, P via cvt_pk into aliased half-buffer, direct epilogue.
// ---------------------------------------------------------------------------
__global__ __launch_bounds__(256) void attn_kernel(
    const u16* __restrict__ Qws, const u16* __restrict__ Kws,
    const u16* __restrict__ Vws, const float* __restrict__ feature,
    float* __restrict__ out)
{
    __shared__ __align__(16) unsigned char smem[32768];

    const int t = threadIdx.x;
    const int wid = t >> 6, lane = t & 63;
    const int i16 = lane & 15, g = lane >> 4;
    const int pt = blockIdx.x, h = blockIdx.y, n = blockIdx.z;
    const int pos0 = pt * 64;
    const size_t qbase = ((size_t)n * HW_ + pos0) * C_ + h * DH_;
    const size_t kbase = ((size_t)n * L_) * C_ + h * DH_;
    const size_t vbase = (size_t)n * C_ * L_ + (size_t)h * DH_ * L_;

    const int q = wid * 16 + i16;

    short8_t bq = *(const short8_t*)&Qws[qbase + (size_t)q * C_ + g * 8];

    #pragma unroll
    for (int p = 0; p < 4; ++p) {
        const int kg = (lane & 3) ^ ((lane >> 3) & 3);
        const int kr = wid * 64 + p * 16 + (lane >> 2);
        const u16* ksrc = Kws + kbase + (size_t)kr * C_ + kg * 8;
        __builtin_amdgcn_global_load_lds(
            (const __attribute__((address_space(1))) void*)ksrc,
            (__attribute__((address_space(3))) void*)(smem + wid * 4096 + p * 1024),
            16, 0, 0);
        const int vd = wid * 8 + p * 2 + (lane >> 5);
        const u16* vsrc = Vws + vbase + (size_t)vd * L_ + ((lane & 31) ^ (vd & 7)) * 8;
        __builtin_amdgcn_global_load_lds(
            (const __attribute__((address_space(1))) void*)vsrc,
            (__attribute__((address_space(3))) void*)(smem + 16384 + wid * 4096 + p * 1024),
            16, 0, 0);
    }
    __syncthreads();

    const int kgr = g ^ ((i16 >> 1) & 3);
    f32x4 s[16];
    #pragma unroll
    for (int nf = 0; nf < 16; ++nf) {
        short8_t a = *(const short8_t*)(smem + (nf * 16 + i16) * 64 + kgr * 16);
        f32x4 z = {0.f, 0.f, 0.f, 0.f};
        s[nf] = __builtin_amdgcn_mfma_f32_16x16x32_bf16(a, bq, z, 0, 0, 0);
    }

    float mm[16], sm[16];
    #pragma unroll
    for (int nf = 0; nf < 16; ++nf)
        mm[nf] = fmaxf(fmaxf(s[nf][0], s[nf][1]), fmaxf(s[nf][2], s[nf][3]));
    #pragma unroll
    for (int st = 8; st >= 1; st >>= 1)
        #pragma unroll
        for (int i = 0; i < 8; ++i)
            if (i < st) mm[i] = fmaxf(mm[i], mm[i + st]);
    float m = mm[0];
    m = fmaxf(m, __shfl_xor(m, 16));
    m = fmaxf(m, __shfl_xor(m, 32));

    const float K2 = 0.25506288f;  // log2(e) / sqrt(32)
    #pragma unroll
    for (int nf = 0; nf < 16; ++nf) {
        #pragma unroll
        for (int r = 0; r < 4; ++r) s[nf][r] = exp2f((s[nf][r] - m) * K2);
        sm[nf] = (s[nf][0] + s[nf][1]) + (s[nf][2] + s[nf][3]);
    }
    #pragma unroll
    for (int st = 8; st >= 1; st >>= 1)
        #pragma unroll
        for (int i = 0; i < 8; ++i)
            if (i < st) sm[i] += sm[i + st];
    float ssum = sm[0];
    ssum += __shfl_xor(ssum, 16);
    ssum += __shfl_xor(ssum, 32);
    const float pinv = 1.0f / ssum;

    __syncthreads();  // Kh dead -> Ph may alias

    f32x4 o0 = {0.f, 0.f, 0.f, 0.f}, o1 = {0.f, 0.f, 0.f, 0.f};
    const int e7 = i16 & 7;

    #pragma unroll
    for (int hb = 0; hb < 2; ++hb) {
        #pragma unroll
        for (int nfp = 0; nfp < 8; ++nfp) {
            const int nf = hb * 8 + nfp;
            #pragma unroll
            for (int w = 0; w < 2; ++w) {
                u32 pw = cvt_pk_bf16(s[nf][2 * w] * pinv, s[nf][2 * w + 1] * pinv);
                const int gran = (nfp * 2 + (g >> 1)) ^ e7;
                *(u32*)(smem + q * 256 + gran * 16 + ((g & 1) * 2 + w) * 4) = pw;
            }
        }
        __syncthreads();
        #pragma unroll
        for (int ks = 0; ks < 4; ++ks) {
            short8_t pb = *(const short8_t*)(smem + q * 256 + (((ks * 4 + g) ^ e7) * 16));
            const int vg = (((hb * 4 + ks) * 4 + g) ^ e7) * 16;
            short8_t va0 = *(const short8_t*)(smem + 16384 + i16 * 512 + vg);
            short8_t va1 = *(const short8_t*)(smem + 16384 + (16 + i16) * 512 + vg);
            o0 = __builtin_amdgcn_mfma_f32_16x16x32_bf16(va0, pb, o0, 0, 0, 0);
            o1 = __builtin_amdgcn_mfma_f32_16x16x32_bf16(va1, pb, o1, 0, 0, 0);
        }
        if (hb == 0) __syncthreads();
    }

    const size_t obase = ((size_t)n * C_ + h * DH_) * HW_ + pos0 + q;
    #pragma unroll
    for (int r = 0; r < 4; ++r) {
        const size_t oa = obase + (size_t)(g * 4 + r) * HW_;
        out[oa] = feature[oa] + o0[r];
        const size_t ob = obase + (size_t)(16 + g * 4 + r) * HW_;
        out[ob] = feature[ob] + o1[r];
    }
}

extern "C" void kernel_launch(void* const* d_in, const int* in_sizes, int n_in,
                              void* d_out, int out_size, void* d_ws, size_t ws_size,
                              hipStream_t stream)
{
    const float* feature = (const float*)d_in[0];
    const float* token   = (const float*)d_in[1];
    const float* wq      = (const float*)d_in[2];
    const float* bq      = (const float*)d_in[3];
    const float* wk      = (const float*)d_in[4];
    const float* bk      = (const float*)d_in[5];
    const float* wv      = (const float*)d_in[6];
    const float* bv      = (const float*)d_in[7];
    float* out = (float*)d_out;

    // ws: Q [16384][512] bf16 (16 MiB) | K [4096][512] (4 MiB) | Vt [n][d][l] (4 MiB)
    u16* Qws = (u16*)d_ws;
    u16* Kws = Qws + (size_t)N_ * HW_ * C_;
    u16* Vws = Kws + (size_t)N_ * L_ * C_;

    proj_kernel<<<dim3(2560), 256, 0, stream>>>(feature, token, wq, bq,
                                                wk, bk, wv, bv,
                                                Qws, Kws, Vws);
    attn_kernel<<<dim3(16, 16, 16), 256, 0, stream>>>(Qws, Kws, Vws, feature, out);
}

// Round 7
// 76.316 us; speedup vs baseline: 1.0401x; 1.0401x over previous
//
#include <hip/hip_runtime.h>
#include <hip/hip_bf16.h>

#define N_ 16
#define L_ 256
#define C_ 512
#define HW_ 1024
#define HEADS_ 16
#define DH_ 32

typedef unsigned short u16;
typedef unsigned int u32;
typedef __attribute__((ext_vector_type(8))) short short8_t;
typedef __attribute__((ext_vector_type(4))) float f32x4;
typedef __attribute__((ext_vector_type(2))) unsigned int u32x2;

__device__ __forceinline__ u16 f2bs(float f) {
    union { float f; u32 i; } x; x.f = f;
    u32 r = x.i + 0x7fffu + ((x.i >> 16) & 1u);
    return (u16)(r >> 16);
}
__device__ __forceinline__ u32 cvt_pk_bf16(float lo, float hi) {
    u32 r;
    asm("v_cvt_pk_bf16_f32 %0, %1, %2" : "=v"(r) : "v"(lo), "v"(hi));
    return r;
}
__device__ __forceinline__ void cvt8(const float* __restrict__ src, void* dst) {
    float4 lo = *(const float4*)src;
    float4 hi = *(const float4*)(src + 4);
    union { u32 w[4]; short8_t v; } pk;
    pk.w[0] = cvt_pk_bf16(lo.x, lo.y);
    pk.w[1] = cvt_pk_bf16(lo.z, lo.w);
    pk.w[2] = cvt_pk_bf16(hi.x, hi.y);
    pk.w[3] = cvt_pk_bf16(hi.z, hi.w);
    *(short8_t*)dst = pk.v;
}
#define AS1(p) (const __attribute__((address_space(1))) void*)(p)
#define AS3(p) (__attribute__((address_space(3))) void*)(p)

// ---------------------------------------------------------------------------
// prep: fp32->bf16: token (524288 f4), wq/wk/wv (65536 f4 each). 2816 blocks.
// ---------------------------------------------------------------------------
__global__ __launch_bounds__(256) void prep_kernel(
    const float* __restrict__ token, const float* __restrict__ wq,
    const float* __restrict__ wk, const float* __restrict__ wv,
    u16* __restrict__ tokb, u16* __restrict__ wqb,
    u16* __restrict__ wkb, u16* __restrict__ wvb)
{
    const int idx = blockIdx.x * 256 + threadIdx.x;
    const float* s; u16* d; int off;
    if (idx < 524288)            { s = token; d = tokb; off = idx; }
    else if (idx < 524288+65536) { s = wq; d = wqb; off = idx - 524288; }
    else if (idx < 524288+131072){ s = wk; d = wkb; off = idx - 524288 - 65536; }
    else                         { s = wv; d = wvb; off = idx - 524288 - 131072; }
    float4 v = ((const float4*)s)[off];
    ushort4 w;
    w.x = f2bs(v.x); w.y = f2bs(v.y); w.z = f2bs(v.z); w.w = f2bs(v.w);
    ((ushort4*)d)[off] = w;
}

// ---------------------------------------------------------------------------
// proj_kernel v2: 128-tiles, global_load_lds staging for bf16 streams,
// XCD-aware L2 blocking.
//  blocks [0,256): KV path — tile 128l x 64d of token GEMM, K and V out.
//  blocks [256,768): QF path — tile 128pos x 128d of feature GEMM
//    (feature fp32 reg-staged + cvt into 160B-padded tr-subtiles).
// Per-XCD mapping: each XCD owns contiguous m-strips x all n-tiles so its
// A-operand region (4MB feature / 512KB token) L2-resides.
// ---------------------------------------------------------------------------
__global__ __launch_bounds__(256) void proj_kernel(
    const float* __restrict__ feature,
    const u16* __restrict__ tokb, const u16* __restrict__ wqb,
    const u16* __restrict__ wkb, const u16* __restrict__ wvb,
    const float* __restrict__ bq, const float* __restrict__ bk,
    const float* __restrict__ bv,
    u16* __restrict__ Qout, u16* __restrict__ Kout, u16* __restrict__ Vt)
{
    __shared__ __align__(16) unsigned char smem[36864];

    const int t = threadIdx.x;
    const int lane = t & 63, wid = t >> 6;
    const int i16 = lane & 15, g = lane >> 4;

    if (blockIdx.x < 256) {
        // ================= KV path: 128 x 64, dual output =================
        const int xcd = blockIdx.x & 7, j = blockIdx.x >> 3;
        const int m0 = (xcd * 4 + (j & 3)) * 128;   // token row tile
        const int n0 = (j >> 2) * 64;               // dout tile
        u16* Tok = (u16*)smem;                      // [128][64] gran-swz, 16KB
        u16* Bk  = (u16*)(smem + 16384);            // [64][64], 8KB
        u16* Bv  = (u16*)(smem + 24576);            // [64][64], 8KB
        u16 (*LTo)[72] = (u16(*)[72])smem;          // K bounce, aliases Tok/Bk

        const int wm = wid >> 1, wn = wid & 1;
        const int r8 = t >> 3, gr = t & 7;

        f32x4 ak[4][2], av[4][2];
        #pragma unroll
        for (int mt = 0; mt < 4; ++mt)
            #pragma unroll
            for (int nt = 0; nt < 2; ++nt) {
                ak[mt][nt] = (f32x4){0.f, 0.f, 0.f, 0.f};
                av[mt][nt] = (f32x4){0.f, 0.f, 0.f, 0.f};
            }

        for (int c0 = 0; c0 < C_; c0 += 64) {
            __syncthreads();
            #pragma unroll
            for (int p = 0; p < 4; ++p) {
                const int row = p * 32 + r8;
                __builtin_amdgcn_global_load_lds(
                    AS1(tokb + (size_t)(m0 + row) * C_ + c0 + ((gr ^ (row & 7)) << 3)),
                    AS3(smem + (p * 32 + wid * 8) * 128), 16, 0, 0);
            }
            #pragma unroll
            for (int p = 0; p < 2; ++p) {
                const int row = p * 32 + r8;
                const int gs = (gr ^ (row & 7)) << 3;
                __builtin_amdgcn_global_load_lds(
                    AS1(wkb + (size_t)(n0 + row) * C_ + c0 + gs),
                    AS3(smem + 16384 + (p * 32 + wid * 8) * 128), 16, 0, 0);
                __builtin_amdgcn_global_load_lds(
                    AS1(wvb + (size_t)(n0 + row) * C_ + c0 + gs),
                    AS3(smem + 24576 + (p * 32 + wid * 8) * 128), 16, 0, 0);
            }
            __syncthreads();
            #pragma unroll
            for (int ks = 0; ks < 2; ++ks) {
                short8_t a[4], bbk[2], bbv[2];
                #pragma unroll
                for (int mt = 0; mt < 4; ++mt) {
                    const int m = wm * 64 + mt * 16 + i16;
                    a[mt] = *(const short8_t*)&Tok[m * 64 + ((((ks << 2) | g) ^ (m & 7)) << 3)];
                }
                #pragma unroll
                for (int nt = 0; nt < 2; ++nt) {
                    const int d = wn * 32 + nt * 16 + i16;
                    const int sw = d * 64 + ((((ks << 2) | g) ^ (d & 7)) << 3);
                    bbk[nt] = *(const short8_t*)&Bk[sw];
                    bbv[nt] = *(const short8_t*)&Bv[sw];
                }
                #pragma unroll
                for (int mt = 0; mt < 4; ++mt)
                    #pragma unroll
                    for (int nt = 0; nt < 2; ++nt) {
                        ak[mt][nt] = __builtin_amdgcn_mfma_f32_16x16x32_bf16(
                            a[mt], bbk[nt], ak[mt][nt], 0, 0, 0);
                        av[mt][nt] = __builtin_amdgcn_mfma_f32_16x16x32_bf16(
                            a[mt], bbv[nt], av[mt][nt], 0, 0, 0);
                    }
            }
        }
        // V direct transposed stores [nb][d][l]
        const int nb = m0 >> 8, l0 = m0 & 255;
        const size_t vtbase = (size_t)nb * C_ * L_;
        #pragma unroll
        for (int nt = 0; nt < 2; ++nt) {
            const int d = n0 + wn * 32 + nt * 16 + i16;
            const float bb = bv[d];
            #pragma unroll
            for (int mt = 0; mt < 4; ++mt) {
                ushort4 w;
                w.x = f2bs(av[mt][nt][0] + bb);
                w.y = f2bs(av[mt][nt][1] + bb);
                w.z = f2bs(av[mt][nt][2] + bb);
                w.w = f2bs(av[mt][nt][3] + bb);
                const int l = l0 + wm * 64 + mt * 16 + g * 4;
                *(ushort4*)&Vt[vtbase + (size_t)d * L_ + l] = w;
            }
        }
        // K through LDS bounce (Tok/Bk dead after barrier)
        __syncthreads();
        #pragma unroll
        for (int nt = 0; nt < 2; ++nt) {
            const int col = wn * 32 + nt * 16 + i16;
            const float bb = bk[n0 + col];
            #pragma unroll
            for (int mt = 0; mt < 4; ++mt)
                #pragma unroll
                for (int r = 0; r < 4; ++r)
                    LTo[wm * 64 + mt * 16 + g * 4 + r][col] =
                        f2bs(ak[mt][nt][r] + bb);
        }
        __syncthreads();
        #pragma unroll
        for (int rep = 0; rep < 4; ++rep) {
            const int m = (t >> 3) + rep * 32;
            const int cs = (t & 7) * 8;
            *(short8_t*)&Kout[(size_t)(m0 + m) * C_ + n0 + cs] = *(short8_t*)&LTo[m][cs];
        }
    } else {
        // ================= QF path: 128 pos x 128 d =================
        const int qid = blockIdx.x - 256;
        const int xcd = qid & 7, j = qid >> 3;
        const int m0 = (xcd * 16 + (j & 15)) * 128;   // global pos-row
        const int n0 = (j >> 4) * 128;                // dout tile
        const int n = m0 >> 10, pos0 = m0 & (HW_ - 1);
        u16* Wt = (u16*)smem;                          // [128][64] gran-swz 16KB
        const int FB = 16384;                          // feature subtiles base

        const int wq_pos = wid >> 1, wq_d = wid & 1;
        const int r8 = t >> 3, gr = t & 7;

        f32x4 acc[4][4];
        #pragma unroll
        for (int dm = 0; dm < 4; ++dm)
            #pragma unroll
            for (int pf = 0; pf < 4; ++pf)
                acc[dm][pf] = (f32x4){0.f, 0.f, 0.f, 0.f};

        for (int c0 = 0; c0 < C_; c0 += 64) {
            __syncthreads();
            // Wq tile via global_load_lds (source granule pre-swizzle)
            #pragma unroll
            for (int p = 0; p < 4; ++p) {
                const int row = p * 32 + r8;
                __builtin_amdgcn_global_load_lds(
                    AS1(wqb + (size_t)(n0 + row) * C_ + c0 + ((gr ^ (row & 7)) << 3)),
                    AS3(smem + (p * 32 + wid * 8) * 128), 16, 0, 0);
            }
            // feature tile 64c x 128pos: 512B row segments, cvt, padded subtiles
            #pragma unroll
            for (int p = 0; p < 4; ++p) {
                const int row = p * 16 + (t >> 4);       // c within tile
                const int pos8 = (t & 15) * 8;
                float f8[8];
                *(float4*)&f8[0] = *(const float4*)&feature[
                    ((size_t)n * C_ + c0 + row) * HW_ + pos0 + pos8];
                *(float4*)&f8[4] = *(const float4*)&feature[
                    ((size_t)n * C_ + c0 + row) * HW_ + pos0 + pos8 + 4];
                const int cb = row >> 2, cr = row & 3;
                const int pb = pos8 >> 4, po = (pos8 & 15) * 2;
                cvt8(f8, smem + FB + (cb * 8 + pb) * 160 + cr * 32 + po);
            }
            __syncthreads();
            #pragma unroll
            for (int ks = 0; ks < 2; ++ks) {
                short8_t a[4], b[4];
                #pragma unroll
                for (int dm = 0; dm < 4; ++dm) {
                    const int m = wq_d * 64 + dm * 16 + i16;
                    a[dm] = *(const short8_t*)&Wt[m * 64 + ((((ks << 2) | g) ^ (m & 7)) << 3)];
                }
                #pragma unroll
                for (int pf = 0; pf < 4; ++pf) {
                    const int pb = wq_pos * 4 + pf;
                    const u32 vaddr = FB +
                        (u32)((ks * 8 + g * 2) * 8 + pb) * 160 + (u32)i16 * 2;
                    u32x2 lo, hi;
                    asm volatile("ds_read_b64_tr_b16 %0, %1"
                                 : "=v"(lo) : "v"(vaddr));
                    asm volatile("ds_read_b64_tr_b16 %0, %1 offset:1280"
                                 : "=v"(hi) : "v"(vaddr));
                    union { u32 w[4]; short8_t v; } pk;
                    pk.w[0] = lo[0]; pk.w[1] = lo[1];
                    pk.w[2] = hi[0]; pk.w[3] = hi[1];
                    b[pf] = pk.v;
                }
                asm volatile("s_waitcnt lgkmcnt(0)" ::: "memory");
                __builtin_amdgcn_sched_barrier(0);
                #pragma unroll
                for (int dm = 0; dm < 4; ++dm)
                    #pragma unroll
                    for (int pf = 0; pf < 4; ++pf)
                        acc[dm][pf] = __builtin_amdgcn_mfma_f32_16x16x32_bf16(
                            a[dm], b[pf], acc[dm][pf], 0, 0, 0);
            }
        }
        // epilogue: rows = d (4 consecutive per lane), col = pos
        #pragma unroll
        for (int dm = 0; dm < 4; ++dm) {
            const int dbase = wq_d * 64 + dm * 16 + g * 4;
            float4 b4 = *(const float4*)&bq[n0 + dbase];
            const float bb[4] = {b4.x, b4.y, b4.z, b4.w};
            #pragma unroll
            for (int pf = 0; pf < 4; ++pf) {
                const int pos = wq_pos * 64 + pf * 16 + i16;
                ushort4 w;
                w.x = f2bs(acc[dm][pf][0] + bb[0]);
                w.y = f2bs(acc[dm][pf][1] + bb[1]);
                w.z = f2bs(acc[dm][pf][2] + bb[2]);
                w.w = f2bs(acc[dm][pf][3] + bb[3]);
                *(ushort4*)&Qout[(size_t)(m0 + pos) * C_ + n0 + dbase] = w;
            }
        }
    }
}

// ---------------------------------------------------------------------------
// attn v2.1 (unchanged from R5/R6, verified).
// ---------------------------------------------------------------------------
__global__ __launch_bounds__(256) void attn_kernel(
    const u16* __restrict__ Qws, const u16* __restrict__ Kws,
    const u16* __restrict__ Vws, const float* __restrict__ feature,
    float* __restrict__ out)
{
    __shared__ __align__(16) unsigned char smem[32768];

    const int t = threadIdx.x;
    const int wid = t >> 6, lane = t & 63;
    const int i16 = lane & 15, g = lane >> 4;
    const int pt = blockIdx.x, h = blockIdx.y, n = blockIdx.z;
    const int pos0 = pt * 64;
    const size_t qbase = ((size_t)n * HW_ + pos0) * C_ + h * DH_;
    const size_t kbase = ((size_t)n * L_) * C_ + h * DH_;
    const size_t vbase = (size_t)n * C_ * L_ + (size_t)h * DH_ * L_;

    const int q = wid * 16 + i16;

    short8_t bq = *(const short8_t*)&Qws[qbase + (size_t)q * C_ + g * 8];

    #pragma unroll
    for (int p = 0; p < 4; ++p) {
        const int kg = (lane & 3) ^ ((lane >> 3) & 3);
        const int kr = wid * 64 + p * 16 + (lane >> 2);
        const u16* ksrc = Kws + kbase + (size_t)kr * C_ + kg * 8;
        __builtin_amdgcn_global_load_lds(AS1(ksrc),
            AS3(smem + wid * 4096 + p * 1024), 16, 0, 0);
        const int vd = wid * 8 + p * 2 + (lane >> 5);
        const u16* vsrc = Vws + vbase + (size_t)vd * L_ + ((lane & 31) ^ (vd & 7)) * 8;
        __builtin_amdgcn_global_load_lds(AS1(vsrc),
            AS3(smem + 16384 + wid * 4096 + p * 1024), 16, 0, 0);
    }
    __syncthreads();

    const int kgr = g ^ ((i16 >> 1) & 3);
    f32x4 s[16];
    #pragma unroll
    for (int nf = 0; nf < 16; ++nf) {
        short8_t a = *(const short8_t*)(smem + (nf * 16 + i16) * 64 + kgr * 16);
        f32x4 z = {0.f, 0.f, 0.f, 0.f};
        s[nf] = __builtin_amdgcn_mfma_f32_16x16x32_bf16(a, bq, z, 0, 0, 0);
    }

    float mm[16], sm[16];
    #pragma unroll
    for (int nf = 0; nf < 16; ++nf)
        mm[nf] = fmaxf(fmaxf(s[nf][0], s[nf][1]), fmaxf(s[nf][2], s[nf][3]));
    #pragma unroll
    for (int st = 8; st >= 1; st >>= 1)
        #pragma unroll
        for (int i = 0; i < 8; ++i)
            if (i < st) mm[i] = fmaxf(mm[i], mm[i + st]);
    float m = mm[0];
    m = fmaxf(m, __shfl_xor(m, 16));
    m = fmaxf(m, __shfl_xor(m, 32));

    const float K2 = 0.25506288f;  // log2(e) / sqrt(32)
    #pragma unroll
    for (int nf = 0; nf < 16; ++nf) {
        #pragma unroll
        for (int r = 0; r < 4; ++r) s[nf][r] = exp2f((s[nf][r] - m) * K2);
        sm[nf] = (s[nf][0] + s[nf][1]) + (s[nf][2] + s[nf][3]);
    }
    #pragma unroll
    for (int st = 8; st >= 1; st >>= 1)
        #pragma unroll
        for (int i = 0; i < 8; ++i)
            if (i < st) sm[i] += sm[i + st];
    float ssum = sm[0];
    ssum += __shfl_xor(ssum, 16);
    ssum += __shfl_xor(ssum, 32);
    const float pinv = 1.0f / ssum;

    __syncthreads();  // Kh dead -> Ph may alias

    f32x4 o0 = {0.f, 0.f, 0.f, 0.f}, o1 = {0.f, 0.f, 0.f, 0.f};
    const int e7 = i16 & 7;

    #pragma unroll
    for (int hb = 0; hb < 2; ++hb) {
        #pragma unroll
        for (int nfp = 0; nfp < 8; ++nfp) {
            const int nf = hb * 8 + nfp;
            #pragma unroll
            for (int w = 0; w < 2; ++w) {
                u32 pw = cvt_pk_bf16(s[nf][2 * w] * pinv, s[nf][2 * w + 1] * pinv);
                const int gran = (nfp * 2 + (g >> 1)) ^ e7;
                *(u32*)(smem + q * 256 + gran * 16 + ((g & 1) * 2 + w) * 4) = pw;
            }
        }
        __syncthreads();
        #pragma unroll
        for (int ks = 0; ks < 4; ++ks) {
            short8_t pb = *(const short8_t*)(smem + q * 256 + (((ks * 4 + g) ^ e7) * 16));
            const int vg = (((hb * 4 + ks) * 4 + g) ^ e7) * 16;
            short8_t va0 = *(const short8_t*)(smem + 16384 + i16 * 512 + vg);
            short8_t va1 = *(const short8_t*)(smem + 16384 + (16 + i16) * 512 + vg);
            o0 = __builtin_amdgcn_mfma_f32_16x16x32_bf16(va0, pb, o0, 0, 0, 0);
            o1 = __builtin_amdgcn_mfma_f32_16x16x32_bf16(va1, pb, o1, 0, 0, 0);
        }
        if (hb == 0) __syncthreads();
    }

    const size_t obase = ((size_t)n * C_ + h * DH_) * HW_ + pos0 + q;
    #pragma unroll
    for (int r = 0; r < 4; ++r) {
        const size_t oa = obase + (size_t)(g * 4 + r) * HW_;
        out[oa] = feature[oa] + o0[r];
        const size_t ob = obase + (size_t)(16 + g * 4 + r) * HW_;
        out[ob] = feature[ob] + o1[r];
    }
}

extern "C" void kernel_launch(void* const* d_in, const int* in_sizes, int n_in,
                              void* d_out, int out_size, void* d_ws, size_t ws_size,
                              hipStream_t stream)
{
    const float* feature = (const float*)d_in[0];
    const float* token   = (const float*)d_in[1];
    const float* wq      = (const float*)d_in[2];
    const float* bq      = (const float*)d_in[3];
    const float* wk      = (const float*)d_in[4];
    const float* bk      = (const float*)d_in[5];
    const float* wv      = (const float*)d_in[6];
    const float* bv      = (const float*)d_in[7];
    float* out = (float*)d_out;

    // ws: Q [16384][512] bf16 (16 MiB) | K [4096][512] (4 MiB) | Vt [n][d][l] (4 MiB)
    u16* Qws = (u16*)d_ws;
    u16* Kws = Qws + (size_t)N_ * HW_ * C_;
    u16* Vws = Kws + (size_t)N_ * L_ * C_;

    // d_out doubles as scratch before attn overwrites it:
    //   [16M,20M): token bf16 | [20M,21.5M): wq/wk/wv bf16
    char* ob = (char*)d_out;
    u16* tokb = (u16*)(ob + (16u << 20));
    u16* wqb  = (u16*)(ob + (20u << 20));
    u16* wkb  = (u16*)(ob + (20u << 20) + 524288);
    u16* wvb  = (u16*)(ob + (20u << 20) + 1048576);

    prep_kernel<<<dim3(2816), 256, 0, stream>>>(token, wq, wk, wv,
                                                tokb, wqb, wkb, wvb);
    proj_kernel<<<dim3(768), 256, 0, stream>>>(feature, tokb, wqb, wkb, wvb,
                                               bq, bk, bv, Qws, Kws, Vws);
    attn_kernel<<<dim3(16, 16, 16), 256, 0, stream>>>(Qws, Kws, Vws, feature, out);
}